// Round 1
// baseline (704.591 us; speedup 1.0000x reference)
//
#include <hip/hip_runtime.h>
#include <hip/hip_bf16.h>
#include <math.h>

#define N_NODES 200000
#define E_DIM   128
#define B_EDGES 4096
#define H_NBRS  20
#define NEG_K   5
#define HID     60

__device__ __forceinline__ float wave_sum(float v) {
  #pragma unroll
  for (int m = 1; m < 64; m <<= 1) v += __shfl_xor(v, m, 64);
  return v;
}
__device__ __forceinline__ float wave_max(float v) {
  #pragma unroll
  for (int m = 1; m < 64; m <<= 1) v = fmaxf(v, __shfl_xor(v, m, 64));
  return v;
}

// ---------------------------------------------------------------------------
// prep: wa1 = W@a1, wa2 = W@a2, wgw = W@gw  (row-wise dots); zero the loss slot
// ---------------------------------------------------------------------------
__global__ void prep_kernel(const float* __restrict__ W,
                            const float* __restrict__ a,
                            const float* __restrict__ gw,
                            float* __restrict__ ws,
                            float* __restrict__ out_loss) {
  int e = threadIdx.x;  // 128 threads, 1 block
  const float* row = W + e * E_DIM;
  float s1 = 0.f, s2 = 0.f, sg = 0.f;
  for (int f = 0; f < E_DIM; ++f) {
    float w = row[f];
    s1 = fmaf(w, a[f], s1);
    s2 = fmaf(w, a[E_DIM + f], s2);
    sg = fmaf(w, gw[f], sg);
  }
  ws[e] = s1;
  ws[E_DIM + e] = s2;
  ws[2 * E_DIM + e] = sg;
  if (e == 0) *out_loss = 0.f;
}

// ---------------------------------------------------------------------------
// MLP: node_emb = relu(nf@W1+b1)@W2+b2.  One row per thread; W1/W2/b via
// uniform (scalar) loads -> v_fmac with SGPR operand; no LDS needed.
// ---------------------------------------------------------------------------
__global__ __launch_bounds__(256) void mlp_kernel(const float* __restrict__ nf,
                                                  const float* __restrict__ W1,
                                                  const float* __restrict__ b1,
                                                  const float* __restrict__ W2,
                                                  const float* __restrict__ b2,
                                                  float* __restrict__ emb) {
  int r = blockIdx.x * 256 + threadIdx.x;
  if (r >= N_NODES) return;
  const float* row = nf + (size_t)r * E_DIM;

  float h[HID];
  #pragma unroll
  for (int j = 0; j < HID; ++j) h[j] = b1[j];

  for (int k4 = 0; k4 < E_DIM / 4; ++k4) {   // rolled (32 iters)
    float4 v = ((const float4*)row)[k4];     // row base is 512B aligned
    const float* w1p = W1 + (k4 * 4) * HID;  // uniform address -> s_load
    #pragma unroll
    for (int kk = 0; kk < 4; ++kk) {
      float vk = (&v.x)[kk];
      #pragma unroll
      for (int j = 0; j < HID; ++j) h[j] = fmaf(vk, w1p[kk * HID + j], h[j]);
    }
  }
  #pragma unroll
  for (int j = 0; j < HID; ++j) h[j] = fmaxf(h[j], 0.f);

  float* out = emb + (size_t)r * E_DIM;      // base only 4B-aligned -> dword stores
  for (int c = 0; c < 4; ++c) {              // rolled (4 chunks of 32 outputs)
    float e[32];
    #pragma unroll
    for (int f = 0; f < 32; ++f) e[f] = b2[c * 32 + f];
    #pragma unroll
    for (int j = 0; j < HID; ++j) {
      float hj = h[j];
      #pragma unroll
      for (int f = 0; f < 32; ++f)
        e[f] = fmaf(hj, W2[j * E_DIM + c * 32 + f], e[f]);  // uniform -> s_load
    }
    #pragma unroll
    for (int f = 0; f < 32; ++f) out[c * 32 + f] = e[f];
  }
}

// ---------------------------------------------------------------------------
// Edge kernel: one block (256 thr) per edge.
// LDS row map: 0=pos0, 1=pos1, 2..21=s_h, 22..41=t_h, 42..46=neg0, 47..51=neg1
// S[] slots: 0 pos, 1..5 neg_s, 6..10 neg_t, 11 sa, 12 ta, 13 p_mu,
// 14..33 sh_a2, 34..53 th_a2, 54..73 p_alpha_s, 74..93 p_alpha_t,
// 94..98 n_mu_s, 99..103 n_mu_t, 104..203 n_alpha_s, 204..303 n_alpha_t,
// 304..323 c_s=att_s*mask, 324..343 c_t, 344..363 c2_s=att*mask*E_s,
// 364..383 c2_t, 500 P_s, 501 P_t, 502 gscale_s, 503 gscale_t, 504/505 glogits
// ---------------------------------------------------------------------------
__global__ __launch_bounds__(256) void edge_kernel(
    const float* __restrict__ emb,
    const int* __restrict__ sources, const int* __restrict__ destinations,
    const float* __restrict__ e_times,
    const int* __restrict__ s_h_nodes, const int* __restrict__ t_h_nodes,
    const float* __restrict__ s_h_times, const float* __restrict__ t_h_times,
    const float* __restrict__ s_maskp, const float* __restrict__ t_maskp,
    const int* __restrict__ neg_src, const int* __restrict__ neg_dst,
    const float* __restrict__ wavec,   // [0..127]=wa1, [128..]=wa2, [256..]=wgw
    const float* __restrict__ delta_s_p, const float* __restrict__ delta_t_p,
    const float* __restrict__ gbp,
    float* __restrict__ out_loss, float* __restrict__ out_pos) {
  __shared__ float embS[52][E_DIM];
  __shared__ float waS[3][E_DIM];
  __shared__ float wsumS[2][E_DIM];
  __shared__ float S[512];
  __shared__ int rows[52];

  const int b = blockIdx.x;
  const int tid = threadIdx.x;
  const int wave = tid >> 6;
  const int lane = tid & 63;

  if (tid < 52) {
    int idx;
    if (tid == 0)       idx = sources[b];
    else if (tid == 1)  idx = destinations[b];
    else if (tid < 22)  idx = s_h_nodes[b * H_NBRS + (tid - 2)];
    else if (tid < 42)  idx = t_h_nodes[b * H_NBRS + (tid - 22)];
    else if (tid < 47)  idx = neg_src[b * NEG_K + (tid - 42)];
    else                idx = neg_dst[b * NEG_K + (tid - 47)];
    rows[tid] = idx;
  }
  if (tid < E_DIM) {
    waS[0][tid] = wavec[tid];
    waS[1][tid] = wavec[E_DIM + tid];
    waS[2][tid] = wavec[2 * E_DIM + tid];
  }
  __syncthreads();

  for (int idx = tid; idx < 52 * E_DIM; idx += 256) {
    int r = idx >> 7, f = idx & 127;
    embS[r][f] = emb[(size_t)rows[r] * E_DIM + f];
  }
  __syncthreads();

  // ---- 304 wave-level dot / squared-distance tasks ----
  for (int t = wave; t < 304; t += 4) {
    int ia, ib, slot; bool sq = false, rl = false;
    if (t < 5)        { ia = 0; ib = 47 + t;        slot = 1 + t; rl = true; }
    else if (t < 10)  { ia = 1; ib = 42 + (t - 5);  slot = 1 + t; rl = true; }
    else if (t == 10) { ia = 0; ib = 1;             slot = 0;     rl = true; }
    else if (t == 11) { ia = 0; ib = 52;            slot = 11; }
    else if (t == 12) { ia = 1; ib = 52;            slot = 12; }
    else if (t == 13) { ia = 0; ib = 1; sq = true;  slot = 13; }
    else if (t < 34)  { ia = 2 + (t - 14);  ib = 53;            slot = t; }
    else if (t < 54)  { ia = 22 + (t - 34); ib = 53;            slot = t; }
    else if (t < 74)  { ia = 2 + (t - 54);  ib = 1;  sq = true; slot = t; }
    else if (t < 94)  { ia = 22 + (t - 74); ib = 0;  sq = true; slot = t; }
    else if (t < 99)  { ia = 0; ib = 47 + (t - 94);  sq = true; slot = t; }
    else if (t < 104) { ia = 1; ib = 42 + (t - 99);  sq = true; slot = t; }
    else if (t < 204) { int q = t - 104; ia = 2 + q / 5;  ib = 47 + q % 5; sq = true; slot = t; }
    else              { int q = t - 204; ia = 22 + q / 5; ib = 42 + q % 5; sq = true; slot = t; }
    const float2* pa = (const float2*)((ia < 52) ? embS[ia] : waS[ia - 52]);
    const float2* pb = (const float2*)((ib < 52) ? embS[ib] : waS[ib - 52]);
    float2 A = pa[lane], Bv = pb[lane];
    float v;
    if (sq) { float dx = A.x - Bv.x, dy = A.y - Bv.y; v = dx * dx + dy * dy; }
    else    { v = A.x * Bv.x + A.y * Bv.y; }
    v = wave_sum(v);
    if (lane == 0) S[slot] = rl ? fmaxf(v, 0.f) : v;
  }
  __syncthreads();

  const int src = rows[0], dst = rows[1];
  const float ds = delta_s_p[src];
  const float dt = delta_t_p[dst];
  const float et = e_times[b];

  // ---- attention / gating scalars: wave0 = s-side, wave1 = t-side ----
  if (wave < 2) {
    const bool is_s = (wave == 0);
    float dval = 0.f, maskv = 0.f, simv = -INFINITY, pa_v = 0.f;
    if (lane < H_NBRS) {
      float ht = is_s ? s_h_times[b * H_NBRS + lane] : t_h_times[b * H_NBRS + lane];
      maskv    = is_s ? s_maskp[b * H_NBRS + lane]  : t_maskp[b * H_NBRS + lane];
      dval = fabsf(et - ht);
      float score = is_s ? (S[11] + S[14 + lane]) : (S[12] + S[34 + lane]);
      float x = expf(-ds * dval) * score;   // reference uses ds for BOTH sims
      simv = (x > 0.f) ? x : 0.2f * x;      // leaky_relu 0.2
      pa_v = is_s ? S[54 + lane] : S[74 + lane];
    }
    float m = wave_max(simv);
    float ev = (lane < H_NBRS) ? expf(simv - m) : 0.f;
    float denom = wave_sum(ev);
    float att = ev / denom;
    float dsum = wave_sum(dval);
    float meand = dsum * (1.f / (float)H_NBRS);
    float dd = is_s ? ds : dt;
    float Eh = expf(dd * dval);
    float pterm = (lane < H_NBRS) ? att * pa_v * Eh * maskv : 0.f;
    float P = wave_sum(pterm);
    if (lane < H_NBRS) {
      int base = is_s ? 304 : 324;
      S[base + lane] = att * maskv;            // c  (for s_hat/t_hat)
      S[base + 40 + lane] = att * maskv * Eh;  // c2 (for lambda sums)
    }
    if (lane == 0) {
      S[500 + wave] = P;
      S[502 + wave] = expf(-dd * meand);       // gate scale
    }
  }
  __syncthreads();

  // ---- weighted neighbor sums (s_hat/t_hat pre-projection) ----
  {
    int e = tid & 127;
    int grp = tid >> 7;  // 0 -> s, 1 -> t
    int cbase = grp ? 324 : 304;
    int ebase = grp ? 22 : 2;
    float acc = 0.f;
    #pragma unroll
    for (int h = 0; h < H_NBRS; ++h)
      acc = fmaf(S[cbase + h], embS[ebase + h][e], acc);
    wsumS[grp][e] = acc;
  }
  __syncthreads();

  // ---- gate logits: tanh(gscale * (wsum . wgw) + gb) ----
  if (wave < 2) {
    const float2* pa = (const float2*)wsumS[wave];
    const float2* pb = (const float2*)waS[2];
    float2 A = pa[lane], Bv = pb[lane];
    float v = wave_sum(A.x * Bv.x + A.y * Bv.y);
    if (lane == 0) S[504 + wave] = tanhf(S[502 + wave] * v + gbp[0]);
  }
  __syncthreads();

  // ---- losses ----
  if (wave == 0) {
    float gls = S[504], glt = S[505];
    float mg = fmaxf(gls, glt);
    float eg_s = expf(gls - mg), eg_t = expf(glt - mg);
    float inv = 1.f / (eg_s + eg_t);
    float ga_s = eg_s * inv, ga_t = eg_t * inv;

    float nl = 0.f;
    if (lane < NEG_K) {
      float acc = 0.f;
      #pragma unroll
      for (int h = 0; h < H_NBRS; ++h) acc = fmaf(S[344 + h], S[104 + h * 5 + lane], acc);
      float nls = S[94 + lane] + ga_s * acc;
      float ns = S[1 + lane];
      // sigmoid(-x) = 1/(1+e^x)
      nl = -logf(1.f / (1.f + expf(nls)) + 1e-6f) * ns * ns;
    } else if (lane < 2 * NEG_K) {
      int n = lane - NEG_K;
      float acc = 0.f;
      #pragma unroll
      for (int h = 0; h < H_NBRS; ++h) acc = fmaf(S[364 + h], S[204 + h * 5 + n], acc);
      float nlt = S[99 + n] + ga_t * acc;
      float ns = S[6 + n];
      nl = -logf(1.f / (1.f + expf(nlt)) + 1e-6f) * ns * ns;
    }
    float nsum = wave_sum(nl);
    if (lane == 0) {
      float p_lambda = S[13] + ga_s * S[500] + ga_t * S[501];
      float pos = S[0];
      float pl = -logf(1.f / (1.f + expf(-p_lambda)) + 1e-6f) * (pos - 1.f) * (pos - 1.f);
      atomicAdd(out_loss, pl * (1.f / 4096.f) + nsum * (1.f / (4096.f * 5.f)));
      out_pos[b] = pos;
    }
  }
}

// ---------------------------------------------------------------------------
extern "C" void kernel_launch(void* const* d_in, const int* in_sizes, int n_in,
                              void* d_out, int out_size, void* d_ws, size_t ws_size,
                              hipStream_t stream) {
  const float* nf           = (const float*)d_in[0];
  const int*   sources      = (const int*)d_in[1];
  const int*   destinations = (const int*)d_in[2];
  const float* e_times      = (const float*)d_in[3];
  const int*   s_h_nodes    = (const int*)d_in[4];
  const int*   t_h_nodes    = (const int*)d_in[5];
  const float* s_h_times    = (const float*)d_in[6];
  const float* t_h_times    = (const float*)d_in[7];
  const float* s_mask       = (const float*)d_in[8];
  const float* t_mask       = (const float*)d_in[9];
  const int*   neg_src      = (const int*)d_in[10];
  const int*   neg_dst      = (const int*)d_in[11];
  const float* W1           = (const float*)d_in[12];
  const float* b1           = (const float*)d_in[13];
  const float* W2           = (const float*)d_in[14];
  const float* b2           = (const float*)d_in[15];
  const float* W            = (const float*)d_in[16];
  const float* a            = (const float*)d_in[17];
  const float* delta_s_p    = (const float*)d_in[18];
  const float* delta_t_p    = (const float*)d_in[19];
  const float* gw           = (const float*)d_in[20];
  const float* gb           = (const float*)d_in[21];

  float* out      = (float*)d_out;
  float* out_loss = out;                       // [0]
  float* out_pos  = out + 1;                   // [1 .. 4096]
  float* emb      = out + 1 + B_EDGES;         // [4097 ..] node_emb (N*E)
  float* ws       = (float*)d_ws;              // wa1 | wa2 | wgw (3*128 floats)

  prep_kernel<<<1, 128, 0, stream>>>(W, a, gw, ws, out_loss);
  mlp_kernel<<<(N_NODES + 255) / 256, 256, 0, stream>>>(nf, W1, b1, W2, b2, emb);
  edge_kernel<<<B_EDGES, 256, 0, stream>>>(emb, sources, destinations, e_times,
      s_h_nodes, t_h_nodes, s_h_times, t_h_times, s_mask, t_mask, neg_src, neg_dst,
      ws, delta_s_p, delta_t_p, gb, out_loss, out_pos);
}

// Round 2
// 580.733 us; speedup vs baseline: 1.2133x; 1.2133x over previous
//
#include <hip/hip_runtime.h>
#include <hip/hip_bf16.h>
#include <math.h>

#define N_NODES 200000
#define E_DIM   128
#define B_EDGES 4096
#define H_NBRS  20
#define NEG_K   5
#define HID     60

__device__ __forceinline__ float wave_sum(float v) {
  #pragma unroll
  for (int m = 1; m < 64; m <<= 1) v += __shfl_xor(v, m, 64);
  return v;
}
__device__ __forceinline__ float wave_max(float v) {
  #pragma unroll
  for (int m = 1; m < 64; m <<= 1) v = fmaxf(v, __shfl_xor(v, m, 64));
  return v;
}

// ---------------------------------------------------------------------------
// prep: wa1 = W@a1, wa2 = W@a2, wgw = W@gw  (row-wise dots); zero the loss slot
// ---------------------------------------------------------------------------
__global__ void prep_kernel(const float* __restrict__ W,
                            const float* __restrict__ a,
                            const float* __restrict__ gw,
                            float* __restrict__ ws,
                            float* __restrict__ out_loss) {
  int e = threadIdx.x;  // 128 threads, 1 block
  const float* row = W + e * E_DIM;
  float s1 = 0.f, s2 = 0.f, sg = 0.f;
  for (int f = 0; f < E_DIM; ++f) {
    float w = row[f];
    s1 = fmaf(w, a[f], s1);
    s2 = fmaf(w, a[E_DIM + f], s2);
    sg = fmaf(w, gw[f], sg);
  }
  ws[e] = s1;
  ws[E_DIM + e] = s2;
  ws[2 * E_DIM + e] = sg;
  if (e == 0) *out_loss = 0.f;
}

// ---------------------------------------------------------------------------
// MLP: node_emb = relu(nf@W1+b1)@W2+b2.  One row per thread.
// Weights staged in LDS (W1 first, then the SAME buffer is overwritten with
// W2 between layers) -> broadcast ds_read_b128, 4 FMA per read. This replaces
// the scalar-cache streaming (60KB per wave per row-batch) that stalled v1.
// ---------------------------------------------------------------------------
__global__ __launch_bounds__(256) void mlp_kernel(const float* __restrict__ nf,
                                                  const float* __restrict__ W1,
                                                  const float* __restrict__ b1,
                                                  const float* __restrict__ W2,
                                                  const float* __restrict__ b2,
                                                  float* __restrict__ emb) {
  __shared__ float wS[E_DIM * HID];  // 30720 B; holds W1, then W2

  const int tid = threadIdx.x;
  const int r = blockIdx.x * 256 + tid;
  const bool active = (r < N_NODES);
  const float* row = nf + (size_t)(active ? r : 0) * E_DIM;

  // stage W1 [128][60]
  for (int i = tid; i < E_DIM * HID; i += 256) wS[i] = W1[i];
  __syncthreads();

  float h[HID];
  #pragma unroll
  for (int j = 0; j < HID; ++j) h[j] = b1[j];

  if (active) {
    for (int k4 = 0; k4 < E_DIM / 4; ++k4) {
      float4 xv = ((const float4*)row)[k4];
      #pragma unroll
      for (int kk = 0; kk < 4; ++kk) {
        float xk = (&xv.x)[kk];
        const float4* wp = (const float4*)&wS[(k4 * 4 + kk) * HID];  // 240B rows, 16B-aligned
        #pragma unroll
        for (int j4 = 0; j4 < HID / 4; ++j4) {
          float4 w = wp[j4];
          h[j4 * 4 + 0] = fmaf(xk, w.x, h[j4 * 4 + 0]);
          h[j4 * 4 + 1] = fmaf(xk, w.y, h[j4 * 4 + 1]);
          h[j4 * 4 + 2] = fmaf(xk, w.z, h[j4 * 4 + 2]);
          h[j4 * 4 + 3] = fmaf(xk, w.w, h[j4 * 4 + 3]);
        }
      }
    }
    #pragma unroll
    for (int j = 0; j < HID; ++j) h[j] = fmaxf(h[j], 0.f);
  }

  // overwrite LDS with W2 [60][128]
  __syncthreads();
  for (int i = tid; i < HID * E_DIM; i += 256) wS[i] = W2[i];
  __syncthreads();

  if (active) {
    float* out = emb + (size_t)r * E_DIM;  // base only 4B-aligned -> dword stores
    for (int c = 0; c < 4; ++c) {          // 4 chunks of 32 outputs
      float e[32];
      #pragma unroll
      for (int f = 0; f < 32; ++f) e[f] = b2[c * 32 + f];
      for (int j = 0; j < HID; ++j) {
        float hj = h[j];
        const float4* wp = (const float4*)&wS[j * E_DIM + c * 32];
        #pragma unroll
        for (int f4 = 0; f4 < 8; ++f4) {
          float4 w = wp[f4];
          e[f4 * 4 + 0] = fmaf(hj, w.x, e[f4 * 4 + 0]);
          e[f4 * 4 + 1] = fmaf(hj, w.y, e[f4 * 4 + 1]);
          e[f4 * 4 + 2] = fmaf(hj, w.z, e[f4 * 4 + 2]);
          e[f4 * 4 + 3] = fmaf(hj, w.w, e[f4 * 4 + 3]);
        }
      }
      #pragma unroll
      for (int f = 0; f < 32; ++f) out[c * 32 + f] = e[f];
    }
  }
}

// ---------------------------------------------------------------------------
// Edge kernel: one block (256 thr) per edge.
// LDS row map: 0=pos0, 1=pos1, 2..21=s_h, 22..41=t_h, 42..46=neg0, 47..51=neg1
// S[] slots: 0 pos, 1..5 neg_s, 6..10 neg_t, 11 sa, 12 ta, 13 p_mu,
// 14..33 sh_a2, 34..53 th_a2, 54..73 p_alpha_s, 74..93 p_alpha_t,
// 94..98 n_mu_s, 99..103 n_mu_t, 104..203 n_alpha_s, 204..303 n_alpha_t,
// 304..323 c_s=att_s*mask, 324..343 c_t, 344..363 c2_s=att*mask*E_s,
// 364..383 c2_t, 500 P_s, 501 P_t, 502 gscale_s, 503 gscale_t, 504/505 glogits
// ---------------------------------------------------------------------------
__global__ __launch_bounds__(256) void edge_kernel(
    const float* __restrict__ emb,
    const int* __restrict__ sources, const int* __restrict__ destinations,
    const float* __restrict__ e_times,
    const int* __restrict__ s_h_nodes, const int* __restrict__ t_h_nodes,
    const float* __restrict__ s_h_times, const float* __restrict__ t_h_times,
    const float* __restrict__ s_maskp, const float* __restrict__ t_maskp,
    const int* __restrict__ neg_src, const int* __restrict__ neg_dst,
    const float* __restrict__ wavec,   // [0..127]=wa1, [128..]=wa2, [256..]=wgw
    const float* __restrict__ delta_s_p, const float* __restrict__ delta_t_p,
    const float* __restrict__ gbp,
    float* __restrict__ out_loss, float* __restrict__ out_pos) {
  __shared__ float embS[52][E_DIM];
  __shared__ float waS[3][E_DIM];
  __shared__ float wsumS[2][E_DIM];
  __shared__ float S[512];
  __shared__ int rows[52];

  const int b = blockIdx.x;
  const int tid = threadIdx.x;
  const int wave = tid >> 6;
  const int lane = tid & 63;

  if (tid < 52) {
    int idx;
    if (tid == 0)       idx = sources[b];
    else if (tid == 1)  idx = destinations[b];
    else if (tid < 22)  idx = s_h_nodes[b * H_NBRS + (tid - 2)];
    else if (tid < 42)  idx = t_h_nodes[b * H_NBRS + (tid - 22)];
    else if (tid < 47)  idx = neg_src[b * NEG_K + (tid - 42)];
    else                idx = neg_dst[b * NEG_K + (tid - 47)];
    rows[tid] = idx;
  }
  if (tid < E_DIM) {
    waS[0][tid] = wavec[tid];
    waS[1][tid] = wavec[E_DIM + tid];
    waS[2][tid] = wavec[2 * E_DIM + tid];
  }
  __syncthreads();

  for (int idx = tid; idx < 52 * E_DIM; idx += 256) {
    int r = idx >> 7, f = idx & 127;
    embS[r][f] = emb[(size_t)rows[r] * E_DIM + f];
  }
  __syncthreads();

  // ---- 304 wave-level dot / squared-distance tasks ----
  for (int t = wave; t < 304; t += 4) {
    int ia, ib, slot; bool sq = false, rl = false;
    if (t < 5)        { ia = 0; ib = 47 + t;        slot = 1 + t; rl = true; }
    else if (t < 10)  { ia = 1; ib = 42 + (t - 5);  slot = 1 + t; rl = true; }
    else if (t == 10) { ia = 0; ib = 1;             slot = 0;     rl = true; }
    else if (t == 11) { ia = 0; ib = 52;            slot = 11; }
    else if (t == 12) { ia = 1; ib = 52;            slot = 12; }
    else if (t == 13) { ia = 0; ib = 1; sq = true;  slot = 13; }
    else if (t < 34)  { ia = 2 + (t - 14);  ib = 53;            slot = t; }
    else if (t < 54)  { ia = 22 + (t - 34); ib = 53;            slot = t; }
    else if (t < 74)  { ia = 2 + (t - 54);  ib = 1;  sq = true; slot = t; }
    else if (t < 94)  { ia = 22 + (t - 74); ib = 0;  sq = true; slot = t; }
    else if (t < 99)  { ia = 0; ib = 47 + (t - 94);  sq = true; slot = t; }
    else if (t < 104) { ia = 1; ib = 42 + (t - 99);  sq = true; slot = t; }
    else if (t < 204) { int q = t - 104; ia = 2 + q / 5;  ib = 47 + q % 5; sq = true; slot = t; }
    else              { int q = t - 204; ia = 22 + q / 5; ib = 42 + q % 5; sq = true; slot = t; }
    const float2* pa = (const float2*)((ia < 52) ? embS[ia] : waS[ia - 52]);
    const float2* pb = (const float2*)((ib < 52) ? embS[ib] : waS[ib - 52]);
    float2 A = pa[lane], Bv = pb[lane];
    float v;
    if (sq) { float dx = A.x - Bv.x, dy = A.y - Bv.y; v = dx * dx + dy * dy; }
    else    { v = A.x * Bv.x + A.y * Bv.y; }
    v = wave_sum(v);
    if (lane == 0) S[slot] = rl ? fmaxf(v, 0.f) : v;
  }
  __syncthreads();

  const int src = rows[0], dst = rows[1];
  const float ds = delta_s_p[src];
  const float dt = delta_t_p[dst];
  const float et = e_times[b];

  // ---- attention / gating scalars: wave0 = s-side, wave1 = t-side ----
  if (wave < 2) {
    const bool is_s = (wave == 0);
    float dval = 0.f, maskv = 0.f, simv = -INFINITY, pa_v = 0.f;
    if (lane < H_NBRS) {
      float ht = is_s ? s_h_times[b * H_NBRS + lane] : t_h_times[b * H_NBRS + lane];
      maskv    = is_s ? s_maskp[b * H_NBRS + lane]  : t_maskp[b * H_NBRS + lane];
      dval = fabsf(et - ht);
      float score = is_s ? (S[11] + S[14 + lane]) : (S[12] + S[34 + lane]);
      float x = expf(-ds * dval) * score;   // reference uses ds for BOTH sims
      simv = (x > 0.f) ? x : 0.2f * x;      // leaky_relu 0.2
      pa_v = is_s ? S[54 + lane] : S[74 + lane];
    }
    float m = wave_max(simv);
    float ev = (lane < H_NBRS) ? expf(simv - m) : 0.f;
    float denom = wave_sum(ev);
    float att = ev / denom;
    float dsum = wave_sum(dval);
    float meand = dsum * (1.f / (float)H_NBRS);
    float dd = is_s ? ds : dt;
    float Eh = expf(dd * dval);
    float pterm = (lane < H_NBRS) ? att * pa_v * Eh * maskv : 0.f;
    float P = wave_sum(pterm);
    if (lane < H_NBRS) {
      int base = is_s ? 304 : 324;
      S[base + lane] = att * maskv;            // c  (for s_hat/t_hat)
      S[base + 40 + lane] = att * maskv * Eh;  // c2 (for lambda sums)
    }
    if (lane == 0) {
      S[500 + wave] = P;
      S[502 + wave] = expf(-dd * meand);       // gate scale
    }
  }
  __syncthreads();

  // ---- weighted neighbor sums (s_hat/t_hat pre-projection) ----
  {
    int e = tid & 127;
    int grp = tid >> 7;  // 0 -> s, 1 -> t
    int cbase = grp ? 324 : 304;
    int ebase = grp ? 22 : 2;
    float acc = 0.f;
    #pragma unroll
    for (int h = 0; h < H_NBRS; ++h)
      acc = fmaf(S[cbase + h], embS[ebase + h][e], acc);
    wsumS[grp][e] = acc;
  }
  __syncthreads();

  // ---- gate logits: tanh(gscale * (wsum . wgw) + gb) ----
  if (wave < 2) {
    const float2* pa = (const float2*)wsumS[wave];
    const float2* pb = (const float2*)waS[2];
    float2 A = pa[lane], Bv = pb[lane];
    float v = wave_sum(A.x * Bv.x + A.y * Bv.y);
    if (lane == 0) S[504 + wave] = tanhf(S[502 + wave] * v + gbp[0]);
  }
  __syncthreads();

  // ---- losses ----
  if (wave == 0) {
    float gls = S[504], glt = S[505];
    float mg = fmaxf(gls, glt);
    float eg_s = expf(gls - mg), eg_t = expf(glt - mg);
    float inv = 1.f / (eg_s + eg_t);
    float ga_s = eg_s * inv, ga_t = eg_t * inv;

    float nl = 0.f;
    if (lane < NEG_K) {
      float acc = 0.f;
      #pragma unroll
      for (int h = 0; h < H_NBRS; ++h) acc = fmaf(S[344 + h], S[104 + h * 5 + lane], acc);
      float nls = S[94 + lane] + ga_s * acc;
      float ns = S[1 + lane];
      // sigmoid(-x) = 1/(1+e^x)
      nl = -logf(1.f / (1.f + expf(nls)) + 1e-6f) * ns * ns;
    } else if (lane < 2 * NEG_K) {
      int n = lane - NEG_K;
      float acc = 0.f;
      #pragma unroll
      for (int h = 0; h < H_NBRS; ++h) acc = fmaf(S[364 + h], S[204 + h * 5 + n], acc);
      float nlt = S[99 + n] + ga_t * acc;
      float ns = S[6 + n];
      nl = -logf(1.f / (1.f + expf(nlt)) + 1e-6f) * ns * ns;
    }
    float nsum = wave_sum(nl);
    if (lane == 0) {
      float p_lambda = S[13] + ga_s * S[500] + ga_t * S[501];
      float pos = S[0];
      float pl = -logf(1.f / (1.f + expf(-p_lambda)) + 1e-6f) * (pos - 1.f) * (pos - 1.f);
      atomicAdd(out_loss, pl * (1.f / 4096.f) + nsum * (1.f / (4096.f * 5.f)));
      out_pos[b] = pos;
    }
  }
}

// ---------------------------------------------------------------------------
extern "C" void kernel_launch(void* const* d_in, const int* in_sizes, int n_in,
                              void* d_out, int out_size, void* d_ws, size_t ws_size,
                              hipStream_t stream) {
  const float* nf           = (const float*)d_in[0];
  const int*   sources      = (const int*)d_in[1];
  const int*   destinations = (const int*)d_in[2];
  const float* e_times      = (const float*)d_in[3];
  const int*   s_h_nodes    = (const int*)d_in[4];
  const int*   t_h_nodes    = (const int*)d_in[5];
  const float* s_h_times    = (const float*)d_in[6];
  const float* t_h_times    = (const float*)d_in[7];
  const float* s_mask       = (const float*)d_in[8];
  const float* t_mask       = (const float*)d_in[9];
  const int*   neg_src      = (const int*)d_in[10];
  const int*   neg_dst      = (const int*)d_in[11];
  const float* W1           = (const float*)d_in[12];
  const float* b1           = (const float*)d_in[13];
  const float* W2           = (const float*)d_in[14];
  const float* b2           = (const float*)d_in[15];
  const float* W            = (const float*)d_in[16];
  const float* a            = (const float*)d_in[17];
  const float* delta_s_p    = (const float*)d_in[18];
  const float* delta_t_p    = (const float*)d_in[19];
  const float* gw           = (const float*)d_in[20];
  const float* gb           = (const float*)d_in[21];

  float* out      = (float*)d_out;
  float* out_loss = out;                       // [0]
  float* out_pos  = out + 1;                   // [1 .. 4096]
  float* emb      = out + 1 + B_EDGES;         // [4097 ..] node_emb (N*E)
  float* ws       = (float*)d_ws;              // wa1 | wa2 | wgw (3*128 floats)

  prep_kernel<<<1, 128, 0, stream>>>(W, a, gw, ws, out_loss);
  mlp_kernel<<<(N_NODES + 255) / 256, 256, 0, stream>>>(nf, W1, b1, W2, b2, emb);
  edge_kernel<<<B_EDGES, 256, 0, stream>>>(emb, sources, destinations, e_times,
      s_h_nodes, t_h_nodes, s_h_times, t_h_times, s_mask, t_mask, neg_src, neg_dst,
      ws, delta_s_p, delta_t_p, gb, out_loss, out_pos);
}

// Round 3
// 319.408 us; speedup vs baseline: 2.2059x; 1.8182x over previous
//
#include <hip/hip_runtime.h>
#include <hip/hip_bf16.h>
#include <math.h>

#define N_NODES 200000
#define E_DIM   128
#define B_EDGES 4096
#define H_NBRS  20
#define NEG_K   5
#define HID     60

typedef short bf16x8 __attribute__((ext_vector_type(8)));
typedef float f32x4  __attribute__((ext_vector_type(4)));

#define MFMA(a, b, c) __builtin_amdgcn_mfma_f32_16x16x32_bf16((a), (b), (c), 0, 0, 0)

__device__ __forceinline__ unsigned short f2b(float f) {  // fp32 -> bf16 RNE
  unsigned u = __float_as_uint(f);
  u += 0x7fffu + ((u >> 16) & 1u);
  return (unsigned short)(u >> 16);
}

__device__ __forceinline__ float wave_sum(float v) {
  #pragma unroll
  for (int m = 1; m < 64; m <<= 1) v += __shfl_xor(v, m, 64);
  return v;
}
__device__ __forceinline__ float wave_max(float v) {
  #pragma unroll
  for (int m = 1; m < 64; m <<= 1) v = fmaxf(v, __shfl_xor(v, m, 64));
  return v;
}

// XOR-swizzled bf16 tile: row stride 128 bf16 (256B); 16B chunk index is
// XORed with (row&3)<<2 so ds_read_b128 A/B-fragment reads are conflict-free.
__device__ __forceinline__ bf16x8 xfrag(const unsigned short* xS, int m, int kk, int q) {
  int chunk = (kk * 4 + q) ^ ((m & 3) << 2);
  return *(const bf16x8*)(xS + m * 128 + chunk * 8);
}

// ---------------------------------------------------------------------------
// prep: pack W1/W2 into MFMA B-fragment order (bf16) in ws; compute
// wa1=W@a1, wa2=W@a2, wgw=W@gw (fp32); zero the loss slot.
// B-frag (16x16x32): lane holds B[k = (lane>>4)*8 + j][n = lane&15], j=0..7.
// ---------------------------------------------------------------------------
__global__ __launch_bounds__(1024) void prep_kernel(
    const float* __restrict__ W, const float* __restrict__ a,
    const float* __restrict__ gw, const float* __restrict__ W1,
    const float* __restrict__ W2, unsigned short* __restrict__ w1f,
    unsigned short* __restrict__ w2f, float* __restrict__ wav,
    float* __restrict__ out_loss) {
  const int tid = threadIdx.x;
  const int lane = tid & 63, grp = tid >> 6;  // 16 groups of 64 lanes
  const int q = lane >> 4, c = lane & 15;

  {  // W1 [128x60] -> frags g = kk*4 + t  (4 ksteps x 4 n-tiles, n padded to 64)
    const int kk = grp >> 2, t = grp & 3;
    const int n = t * 16 + c, k0 = kk * 32 + q * 8;
    unsigned v[4];
    #pragma unroll
    for (int jj = 0; jj < 4; ++jj) {
      unsigned short lo = (n < 60) ? f2b(W1[(k0 + 2 * jj) * 60 + n]) : 0;
      unsigned short hi = (n < 60) ? f2b(W1[(k0 + 2 * jj + 1) * 60 + n]) : 0;
      v[jj] = (unsigned)lo | ((unsigned)hi << 16);
    }
    ((uint4*)w1f)[grp * 64 + lane] = make_uint4(v[0], v[1], v[2], v[3]);
  }
  {  // W2 [60x128] -> frags g = ks*8 + t  (2 ksteps (K padded 60->64) x 8 n-tiles)
    const int ks = grp >> 3, t = grp & 7;
    const int n = t * 16 + c, k0 = ks * 32 + q * 8;
    unsigned v[4];
    #pragma unroll
    for (int jj = 0; jj < 4; ++jj) {
      int k = k0 + 2 * jj;
      unsigned short lo = (k < 60) ? f2b(W2[k * 128 + n]) : 0;
      unsigned short hi = (k + 1 < 60) ? f2b(W2[(k + 1) * 128 + n]) : 0;
      v[jj] = (unsigned)lo | ((unsigned)hi << 16);
    }
    ((uint4*)w2f)[grp * 64 + lane] = make_uint4(v[0], v[1], v[2], v[3]);
  }
  if (tid < 128) {
    const float* row = W + tid * E_DIM;
    float s1 = 0.f, s2 = 0.f, sg = 0.f;
    for (int f = 0; f < E_DIM; ++f) {
      float w = row[f];
      s1 = fmaf(w, a[f], s1);
      s2 = fmaf(w, a[E_DIM + f], s2);
      sg = fmaf(w, gw[f], sg);
    }
    wav[tid] = s1; wav[E_DIM + tid] = s2; wav[2 * E_DIM + tid] = sg;
  }
  if (tid == 0) *out_loss = 0.f;
}

// ---------------------------------------------------------------------------
// MLP via MFMA: emb = relu(nf@W1+b1)@W2+b2. Block = 64 rows, wave = 16 rows.
// All LDS tiles are wave-private -> NO __syncthreads (no barrier drain).
// ---------------------------------------------------------------------------
__global__ __launch_bounds__(256) void mlp_kernel(
    const float* __restrict__ nf, const unsigned short* __restrict__ w1f,
    const unsigned short* __restrict__ w2f, const float* __restrict__ b1,
    const float* __restrict__ b2, float* __restrict__ emb) {
  __shared__ unsigned short aS[4][16 * 128];  // per-wave A tile (bf16, swizzled)
  __shared__ float cS[4][16 * 68];            // per-wave hidden tile (f32, stride 68)

  const int tid = threadIdx.x, wave = tid >> 6, lane = tid & 63;
  const int q = lane >> 4, c = lane & 15;
  unsigned short* aw = aS[wave];
  float* cw = cS[wave];
  const size_t R = (size_t)blockIdx.x * 64 + wave * 16;  // 3125*64 == 200000 exactly

  // stage 16 rows x 128 f32 -> bf16 swizzled LDS (8 float4 per lane)
  #pragma unroll
  for (int it = 0; it < 8; ++it) {
    int v = it * 64 + lane;          // 0..511
    int r = v >> 5, c4 = v & 31;
    float4 x = *(const float4*)(nf + (R + r) * E_DIM + c4 * 4);
    int chunk = c4 >> 1, half = c4 & 1;
    int phys = r * 128 + (((chunk ^ ((r & 3) << 2))) << 3) + (half << 2);
    *(ushort4*)&aw[phys] = make_ushort4(f2b(x.x), f2b(x.y), f2b(x.z), f2b(x.w));
  }

  // layer 1: C1[16x64] = A[16x128] @ W1[128x64]
  bf16x8 w1[16];
  #pragma unroll
  for (int g = 0; g < 16; ++g) w1[g] = *(const bf16x8*)(w1f + (g * 64 + lane) * 8);

  f32x4 acc1[4] = {};
  #pragma unroll
  for (int kk = 0; kk < 4; ++kk) {
    bf16x8 av = xfrag(aw, c, kk, q);  // A: m = lane&15, k = kk*32 + q*8 + j
    #pragma unroll
    for (int t = 0; t < 4; ++t) acc1[t] = MFMA(av, w1[kk * 4 + t], acc1[t]);
  }
  // bias + relu -> cS (C/D layout: row = q*4+i, col = lane&15 within tile)
  #pragma unroll
  for (int t = 0; t < 4; ++t) {
    int n = t * 16 + c;
    float bv = (n < 60) ? b1[n] : 0.f;
    #pragma unroll
    for (int i = 0; i < 4; ++i)
      cw[(q * 4 + i) * 68 + n] = fmaxf(acc1[t][i] + bv, 0.f);
  }

  // A2 frags from cS: row m = lane&15, k = ks*32 + q*8 + j
  bf16x8 a2[2];
  #pragma unroll
  for (int ks = 0; ks < 2; ++ks) {
    f32x4 r0 = *(const f32x4*)&cw[c * 68 + ks * 32 + q * 8];
    f32x4 r1 = *(const f32x4*)&cw[c * 68 + ks * 32 + q * 8 + 4];
    bf16x8 t8;
    #pragma unroll
    for (int j = 0; j < 4; ++j) {
      t8[j] = (short)f2b(r0[j]);
      t8[4 + j] = (short)f2b(r1[j]);
    }
    a2[ks] = t8;
  }

  // layer 2: emb[16x128] = relu(C1)[16x64] @ W2[64x128]
  bf16x8 w2r[16];
  #pragma unroll
  for (int g = 0; g < 16; ++g) w2r[g] = *(const bf16x8*)(w2f + (g * 64 + lane) * 8);

  f32x4 acc2[8] = {};
  #pragma unroll
  for (int ks = 0; ks < 2; ++ks)
    #pragma unroll
    for (int t = 0; t < 8; ++t) acc2[t] = MFMA(a2[ks], w2r[ks * 8 + t], acc2[t]);

  #pragma unroll
  for (int t = 0; t < 8; ++t) {
    int n = t * 16 + c;
    float bv = b2[n];
    #pragma unroll
    for (int i = 0; i < 4; ++i)
      emb[(R + q * 4 + i) * E_DIM + n] = acc2[t][i] + bv;
  }
}

// ---------------------------------------------------------------------------
// Edge kernel: one block per edge. Build X[64x128] = 55 vectors (bf16), Gram
// G = X@X^T via MFMA, then all dots/sq-dists/linear-projection scalars come
// from G. Row map: 0=pos0, 1=pos1, 2..21=s_h, 22..41=t_h, 42..46=neg0,
// 47..51=neg1, 52=W@a1, 53=W@a2, 54=W@gw, 55..63=zero.
// S[]: 0..19 c2_s, 20..39 c2_t, 40 P_s, 41 P_t, 42 glogit_s, 43 glogit_t.
// ---------------------------------------------------------------------------
__global__ __launch_bounds__(256) void edge_kernel(
    const float* __restrict__ emb,
    const int* __restrict__ sources, const int* __restrict__ destinations,
    const float* __restrict__ e_times,
    const int* __restrict__ s_h_nodes, const int* __restrict__ t_h_nodes,
    const float* __restrict__ s_h_times, const float* __restrict__ t_h_times,
    const float* __restrict__ s_maskp, const float* __restrict__ t_maskp,
    const int* __restrict__ neg_src, const int* __restrict__ neg_dst,
    const float* __restrict__ wav,
    const float* __restrict__ delta_s_p, const float* __restrict__ delta_t_p,
    const float* __restrict__ gbp,
    float* __restrict__ out_loss, float* __restrict__ out_pos) {
  __shared__ unsigned short xS[64 * 128];  // 16 KB bf16 swizzled
  __shared__ float gS[64 * 65];            // 16.6 KB Gram
  __shared__ float S[64];
  __shared__ int rows[52];

  const int b = blockIdx.x;
  const int tid = threadIdx.x;
  const int wave = tid >> 6, lane = tid & 63;
  const int q = lane >> 4, c = lane & 15;

  if (tid < 52) {
    int idx;
    if (tid == 0)       idx = sources[b];
    else if (tid == 1)  idx = destinations[b];
    else if (tid < 22)  idx = s_h_nodes[b * H_NBRS + (tid - 2)];
    else if (tid < 42)  idx = t_h_nodes[b * H_NBRS + (tid - 22)];
    else if (tid < 47)  idx = neg_src[b * NEG_K + (tid - 42)];
    else                idx = neg_dst[b * NEG_K + (tid - 47)];
    rows[tid] = idx;
  }
  __syncthreads();

  // stage X: 64 rows x 128 -> bf16 (2048 float4 units over 256 threads)
  #pragma unroll
  for (int it = 0; it < 8; ++it) {
    int v = it * 256 + tid;
    int r = v >> 5, c4 = v & 31;
    float4 x;
    if (r < 52)      x = *(const float4*)(emb + (size_t)rows[r] * E_DIM + c4 * 4);
    else if (r < 55) x = *(const float4*)(wav + (r - 52) * E_DIM + c4 * 4);
    else             x = make_float4(0.f, 0.f, 0.f, 0.f);
    int chunk = c4 >> 1, half = c4 & 1;
    int phys = r * 128 + (((chunk ^ ((r & 3) << 2))) << 3) + (half << 2);
    *(ushort4*)&xS[phys] = make_ushort4(f2b(x.x), f2b(x.y), f2b(x.z), f2b(x.w));
  }
  __syncthreads();

  // Gram: wave w computes rows [w*16, w*16+16) x all 64 cols
  {
    f32x4 acc[4] = {};
    #pragma unroll
    for (int kk = 0; kk < 4; ++kk) {
      bf16x8 av = xfrag(xS, wave * 16 + c, kk, q);
      #pragma unroll
      for (int t = 0; t < 4; ++t) {
        bf16x8 bv = xfrag(xS, t * 16 + c, kk, q);  // B[k][n] = X[n][k]
        acc[t] = MFMA(av, bv, acc[t]);
      }
    }
    #pragma unroll
    for (int t = 0; t < 4; ++t)
      #pragma unroll
      for (int i = 0; i < 4; ++i)
        gS[(wave * 16 + q * 4 + i) * 65 + t * 16 + c] = acc[t][i];
  }
  __syncthreads();

  const float ds = delta_s_p[rows[0]];
  const float dt = delta_t_p[rows[1]];
  const float et = e_times[b];
  const float gb0 = gbp[0];

  // attention / gating: wave0 = s-side, wave1 = t-side
  if (wave < 2) {
    const bool is_s = (wave == 0);
    const int self_ = is_s ? 0 : 1, other = is_s ? 1 : 0;
    const float dd = is_s ? ds : dt;
    float dval = 0.f, maskv = 0.f, simv = -INFINITY, pav = 0.f, gdot = 0.f;
    if (lane < H_NBRS) {
      int hr = (is_s ? 2 : 22) + lane;
      float ht = is_s ? s_h_times[b * H_NBRS + lane] : t_h_times[b * H_NBRS + lane];
      maskv    = is_s ? s_maskp[b * H_NBRS + lane]   : t_maskp[b * H_NBRS + lane];
      dval = fabsf(et - ht);
      float score = gS[self_ * 65 + 52] + gS[hr * 65 + 53];
      float x = expf(-ds * dval) * score;  // reference uses ds for BOTH sims
      simv = (x > 0.f) ? x : 0.2f * x;     // leaky_relu 0.2
      pav = gS[hr * 65 + hr] + gS[other * 65 + other] - 2.f * gS[hr * 65 + other];
      gdot = gS[hr * 65 + 54];
    }
    float m = wave_max(simv);
    float ev = (lane < H_NBRS) ? expf(simv - m) : 0.f;
    float att = ev / wave_sum(ev);
    float meand = wave_sum(dval) * (1.f / (float)H_NBRS);
    float Eh = expf(dd * dval);
    float cm = att * maskv;
    float P = wave_sum((lane < H_NBRS) ? cm * pav * Eh : 0.f);
    float gsum = wave_sum((lane < H_NBRS) ? cm * gdot : 0.f);
    if (lane < H_NBRS) S[(is_s ? 0 : 20) + lane] = cm * Eh;
    if (lane == 0) {
      S[40 + wave] = P;
      S[42 + wave] = tanhf(expf(-dd * meand) * gsum + gb0);
    }
  }
  __syncthreads();

  // losses (wave 0)
  if (wave == 0) {
    float gls = S[42], glt = S[43];
    float mg = fmaxf(gls, glt);
    float eg_s = expf(gls - mg), eg_t = expf(glt - mg);
    float inv = 1.f / (eg_s + eg_t);
    float ga_s = eg_s * inv, ga_t = eg_t * inv;

    float nl = 0.f;
    if (lane < NEG_K) {  // s-side negatives
      int nr = 47 + lane;
      float diag_n = gS[nr * 65 + nr];
      float n_mu = gS[0] + diag_n - 2.f * gS[0 * 65 + nr];
      float acc = 0.f;
      #pragma unroll
      for (int h = 0; h < H_NBRS; ++h) {
        int hr = 2 + h;
        acc = fmaf(S[h], gS[hr * 65 + hr] + diag_n - 2.f * gS[hr * 65 + nr], acc);
      }
      float nls = n_mu + ga_s * acc;
      float ns = fmaxf(gS[0 * 65 + nr], 0.f);  // relu(pos0 . neg1[n])
      nl = -logf(1.f / (1.f + expf(nls)) + 1e-6f) * ns * ns;
    } else if (lane < 2 * NEG_K) {  // t-side negatives
      int n = lane - NEG_K;
      int nr = 42 + n;
      float diag_n = gS[nr * 65 + nr];
      float n_mu = gS[1 * 65 + 1] + diag_n - 2.f * gS[1 * 65 + nr];
      float acc = 0.f;
      #pragma unroll
      for (int h = 0; h < H_NBRS; ++h) {
        int hr = 22 + h;
        acc = fmaf(S[20 + h], gS[hr * 65 + hr] + diag_n - 2.f * gS[hr * 65 + nr], acc);
      }
      float nlt = n_mu + ga_t * acc;
      float ns = fmaxf(gS[1 * 65 + nr], 0.f);  // relu(pos1 . neg0[n])
      nl = -logf(1.f / (1.f + expf(nlt)) + 1e-6f) * ns * ns;
    }
    float nsum = wave_sum(nl);
    if (lane == 0) {
      float p_mu = gS[0] + gS[65 + 1] - 2.f * gS[1];
      float p_lambda = p_mu + ga_s * S[40] + ga_t * S[41];
      float pos = fmaxf(gS[1], 0.f);
      float pl = -logf(1.f / (1.f + expf(-p_lambda)) + 1e-6f) * (pos - 1.f) * (pos - 1.f);
      atomicAdd(out_loss, pl * (1.f / 4096.f) + nsum * (1.f / (4096.f * 5.f)));
      out_pos[b] = pos;
    }
  }
}

// ---------------------------------------------------------------------------
extern "C" void kernel_launch(void* const* d_in, const int* in_sizes, int n_in,
                              void* d_out, int out_size, void* d_ws, size_t ws_size,
                              hipStream_t stream) {
  const float* nf           = (const float*)d_in[0];
  const int*   sources      = (const int*)d_in[1];
  const int*   destinations = (const int*)d_in[2];
  const float* e_times      = (const float*)d_in[3];
  const int*   s_h_nodes    = (const int*)d_in[4];
  const int*   t_h_nodes    = (const int*)d_in[5];
  const float* s_h_times    = (const float*)d_in[6];
  const float* t_h_times    = (const float*)d_in[7];
  const float* s_mask       = (const float*)d_in[8];
  const float* t_mask       = (const float*)d_in[9];
  const int*   neg_src      = (const int*)d_in[10];
  const int*   neg_dst      = (const int*)d_in[11];
  const float* W1           = (const float*)d_in[12];
  const float* b1           = (const float*)d_in[13];
  const float* W2           = (const float*)d_in[14];
  const float* b2           = (const float*)d_in[15];
  const float* W            = (const float*)d_in[16];
  const float* a            = (const float*)d_in[17];
  const float* delta_s_p    = (const float*)d_in[18];
  const float* delta_t_p    = (const float*)d_in[19];
  const float* gw           = (const float*)d_in[20];
  const float* gb           = (const float*)d_in[21];

  float* out      = (float*)d_out;
  float* out_loss = out;                 // [0]
  float* out_pos  = out + 1;             // [1 .. 4096]
  float* emb      = out + 1 + B_EDGES;   // [4097 ..] node_emb (N*E)

  // ws layout: w1f 16KB | w2f 16KB | wav 3*128 f32
  unsigned short* w1f = (unsigned short*)d_ws;
  unsigned short* w2f = w1f + 8192;
  float*          wav = (float*)(w2f + 8192);

  prep_kernel<<<1, 1024, 0, stream>>>(W, a, gw, W1, W2, w1f, w2f, wav, out_loss);
  mlp_kernel<<<N_NODES / 64, 256, 0, stream>>>(nf, w1f, w2f, b1, b2, emb);
  edge_kernel<<<B_EDGES, 256, 0, stream>>>(emb, sources, destinations, e_times,
      s_h_nodes, t_h_nodes, s_h_times, t_h_times, s_mask, t_mask, neg_src, neg_dst,
      wav, delta_s_p, delta_t_p, gb, out_loss, out_pos);
}